// Round 4
// baseline (534.142 us; speedup 1.0000x reference)
//
#include <hip/hip_runtime.h>

#define HD 64  // hidden dim

// ---------------------------------------------------------------------------
// GEMM: Y[n x 64] = X[n x K] @ W[K x 64]   (used only for the F=128 input GEMM)
// k-loop NOT fully unrolled (round-1 lesson: full unroll -> 256 VGPR + spill).
// ---------------------------------------------------------------------------
template <int K>
__global__ __launch_bounds__(256) void gemm_k(const float* __restrict__ X,
                                              const float* __restrict__ W,
                                              float* __restrict__ Y, int n) {
    __shared__ float Ws[K][HD];
    __shared__ float Xs[64][K];

    const int tid  = threadIdx.x;
    const int lane = tid & 63;
    const int wid  = tid >> 6;
    const int row0 = blockIdx.x * 64;

    for (int i = tid; i < K * HD; i += 256) Ws[i >> 6][i & 63] = W[i];
    {
        const int rowf4 = K / 4;
        const float4* Xg = (const float4*)X;
        float4* Xl = (float4*)&Xs[0][0];
        for (int i = tid; i < 64 * rowf4; i += 256) {
            const int r   = i / rowf4;
            const int row = row0 + r;
            float4 v = make_float4(0.f, 0.f, 0.f, 0.f);
            if (row < n) v = Xg[(size_t)row * rowf4 + (i - r * rowf4)];
            Xl[i] = v;
        }
    }
    __syncthreads();

    float acc[16];
#pragma unroll
    for (int r = 0; r < 16; ++r) acc[r] = 0.f;

    const int rbase = wid * 16;
#pragma unroll 1
    for (int k0 = 0; k0 < K; k0 += 8) {
        float wreg[8];
#pragma unroll
        for (int j = 0; j < 8; ++j) wreg[j] = Ws[k0 + j][lane];
#pragma unroll
        for (int r = 0; r < 16; ++r) {
            const float4 x0 = *(const float4*)&Xs[rbase + r][k0 + 0];
            const float4 x1 = *(const float4*)&Xs[rbase + r][k0 + 4];
            float a = acc[r];
            a = fmaf(wreg[0], x0.x, a);
            a = fmaf(wreg[1], x0.y, a);
            a = fmaf(wreg[2], x0.z, a);
            a = fmaf(wreg[3], x0.w, a);
            a = fmaf(wreg[4], x1.x, a);
            a = fmaf(wreg[5], x1.y, a);
            a = fmaf(wreg[6], x1.z, a);
            a = fmaf(wreg[7], x1.w, a);
            acc[r] = a;
        }
    }

#pragma unroll
    for (int r = 0; r < 16; ++r) {
        const int row = row0 + rbase + r;
        if (row < n) Y[(size_t)row * HD + lane] = acc[r];
    }
}

// ---------------------------------------------------------------------------
// CSR build (round-2 lesson: 64M fp32 atomics = 850 us/pass; int-ticket CSR
// + gather is ~10x cheaper). fill order nondeterministic but slot ranges
// are contiguous per node regardless of order.
// ---------------------------------------------------------------------------
__global__ __launch_bounds__(256) void count_deg(const int* __restrict__ dst,
                                                 int* __restrict__ deg, int E) {
    const int t = blockIdx.x * 256 + threadIdx.x;
    if (t < E) atomicAdd(&deg[dst[t]], 1);
}

__global__ __launch_bounds__(256) void assign_starts(const int* __restrict__ deg,
                                                     int* __restrict__ start,
                                                     int* __restrict__ fillpos,
                                                     int* __restrict__ cursor, int n) {
    const int t     = blockIdx.x * 256 + threadIdx.x;
    const int lane  = threadIdx.x & 63;
    const int base4 = t * 4;
    int d[4];
    int tot = 0;
#pragma unroll
    for (int i = 0; i < 4; ++i) {
        d[i] = (base4 + i < n) ? deg[base4 + i] : 0;
        tot += d[i];
    }
    int pfx = tot;
#pragma unroll
    for (int off = 1; off < 64; off <<= 1) {
        const int y = __shfl_up(pfx, off);
        if (lane >= off) pfx += y;
    }
    const int excl = pfx - tot;
    int base = 0;
    if (lane == 63) base = atomicAdd(cursor, pfx);
    base = __shfl(base, 63);
    int s = base + excl;
#pragma unroll
    for (int i = 0; i < 4; ++i) {
        if (base4 + i < n) {
            start[base4 + i]   = s;
            fillpos[base4 + i] = s;
        }
        s += d[i];
    }
}

__global__ __launch_bounds__(256) void fill_csr(const int* __restrict__ src,
                                                const int* __restrict__ dst,
                                                int* __restrict__ fillpos,
                                                int* __restrict__ eidx, int E) {
    const int t = blockIdx.x * 256 + threadIdx.x;
    if (t < E) {
        const int p = atomicAdd(&fillpos[dst[t]], 1);
        eidx[p] = src[t];
    }
}

// ---------------------------------------------------------------------------
// Fused GIN layer (middle): reads y1, writes y2 = h1@Wn where
//   t  = relu(y1[v] + sum_{u in N(v)} y1[u] + bpre)   (gather-PRE into LDS)
//   h1 = relu(t@Wb + bb)                              (registers -> LDS reuse)
//   y2 = h1@Wn                                        (written to HBM)
// h1 and agg never touch HBM. Each wave owns rows [wid*16, wid*16+16):
// matmul k-loops read only the wave's own LDS rows, so the t->h1 overwrite
// needs only intra-block barriers.
// ---------------------------------------------------------------------------
__global__ __launch_bounds__(256) void layer_mid(const float* __restrict__ Y,
                                                 const int* __restrict__ start,
                                                 const int* __restrict__ endp,
                                                 const int* __restrict__ eidx,
                                                 const float* __restrict__ bpre,
                                                 const float* __restrict__ Wb,
                                                 const float* __restrict__ bb,
                                                 const float* __restrict__ Wn,
                                                 float* __restrict__ Yout, int n) {
    __shared__ float Xs[64][HD];
    __shared__ float Ws1[HD][HD];
    __shared__ float Ws2[HD][HD];

    const int tid  = threadIdx.x;
    const int lane = tid & 63;
    const int wid  = tid >> 6;
    const int row0 = blockIdx.x * 64;

    for (int i = tid; i < HD * HD; i += 256) {
        Ws1[i >> 6][i & 63] = Wb[i];
        Ws2[i >> 6][i & 63] = Wn[i];
    }

    // gather-PRE staging: one wave per row, lane = column
    const float bp = bpre[lane];
    for (int r = wid; r < 64; r += 4) {
        const int v = row0 + r;
        float a = 0.f;
        if (v < n) {
            a = Y[(size_t)v * HD + lane];
            const int s = start[v];
            const int e = endp[v];
            int j = s;
            for (; j + 1 < e; j += 2) {
                const int u0 = eidx[j];
                const int u1 = eidx[j + 1];
                a += Y[(size_t)u0 * HD + lane] + Y[(size_t)u1 * HD + lane];
            }
            if (j < e) a += Y[(size_t)eidx[j] * HD + lane];
            a = fmaxf(a + bp, 0.f);
        }
        Xs[r][lane] = a;
    }
    __syncthreads();

    const int rbase = wid * 16;
    float acc[16];
#pragma unroll
    for (int r = 0; r < 16; ++r) acc[r] = 0.f;

#pragma unroll 1
    for (int k0 = 0; k0 < HD; k0 += 8) {
        float wreg[8];
#pragma unroll
        for (int j = 0; j < 8; ++j) wreg[j] = Ws1[k0 + j][lane];
#pragma unroll
        for (int r = 0; r < 16; ++r) {
            const float4 x0 = *(const float4*)&Xs[rbase + r][k0 + 0];
            const float4 x1 = *(const float4*)&Xs[rbase + r][k0 + 4];
            float a = acc[r];
            a = fmaf(wreg[0], x0.x, a);
            a = fmaf(wreg[1], x0.y, a);
            a = fmaf(wreg[2], x0.z, a);
            a = fmaf(wreg[3], x0.w, a);
            a = fmaf(wreg[4], x1.x, a);
            a = fmaf(wreg[5], x1.y, a);
            a = fmaf(wreg[6], x1.z, a);
            a = fmaf(wreg[7], x1.w, a);
            acc[r] = a;
        }
    }
    __syncthreads();          // all waves done reading t from Xs

    const float bbv = bb[lane];
#pragma unroll
    for (int r = 0; r < 16; ++r) Xs[rbase + r][lane] = fmaxf(acc[r] + bbv, 0.f);
    __syncthreads();          // h1 staged

    float acc2[16];
#pragma unroll
    for (int r = 0; r < 16; ++r) acc2[r] = 0.f;

#pragma unroll 1
    for (int k0 = 0; k0 < HD; k0 += 8) {
        float wreg[8];
#pragma unroll
        for (int j = 0; j < 8; ++j) wreg[j] = Ws2[k0 + j][lane];
#pragma unroll
        for (int r = 0; r < 16; ++r) {
            const float4 x0 = *(const float4*)&Xs[rbase + r][k0 + 0];
            const float4 x1 = *(const float4*)&Xs[rbase + r][k0 + 4];
            float a = acc2[r];
            a = fmaf(wreg[0], x0.x, a);
            a = fmaf(wreg[1], x0.y, a);
            a = fmaf(wreg[2], x0.z, a);
            a = fmaf(wreg[3], x0.w, a);
            a = fmaf(wreg[4], x1.x, a);
            a = fmaf(wreg[5], x1.y, a);
            a = fmaf(wreg[6], x1.z, a);
            a = fmaf(wreg[7], x1.w, a);
            acc2[r] = a;
        }
    }

#pragma unroll
    for (int r = 0; r < 16; ++r) {
        const int row = row0 + rbase + r;
        if (row < n) Yout[(size_t)row * HD + lane] = acc2[r];
    }
}

// ---------------------------------------------------------------------------
// Fused GIN layer (final): reads y2, computes h2 = relu(t2@Wb + bb) in
// registers, pools directly into sums/counts (batch sorted -> run-accumulate
// over the wave's 16 consecutive rows, one atomic row per run). h2 never
// written to HBM.
// ---------------------------------------------------------------------------
__global__ __launch_bounds__(256) void layer_end(const float* __restrict__ Y,
                                                 const int* __restrict__ start,
                                                 const int* __restrict__ endp,
                                                 const int* __restrict__ eidx,
                                                 const float* __restrict__ bpre,
                                                 const float* __restrict__ Wb,
                                                 const float* __restrict__ bb,
                                                 const int* __restrict__ batch,
                                                 float* __restrict__ sums,
                                                 float* __restrict__ counts, int n) {
    __shared__ float Xs[64][HD];
    __shared__ float Ws1[HD][HD];

    const int tid  = threadIdx.x;
    const int lane = tid & 63;
    const int wid  = tid >> 6;
    const int row0 = blockIdx.x * 64;

    for (int i = tid; i < HD * HD; i += 256) Ws1[i >> 6][i & 63] = Wb[i];

    const float bp = bpre[lane];
    for (int r = wid; r < 64; r += 4) {
        const int v = row0 + r;
        float a = 0.f;
        if (v < n) {
            a = Y[(size_t)v * HD + lane];
            const int s = start[v];
            const int e = endp[v];
            int j = s;
            for (; j + 1 < e; j += 2) {
                const int u0 = eidx[j];
                const int u1 = eidx[j + 1];
                a += Y[(size_t)u0 * HD + lane] + Y[(size_t)u1 * HD + lane];
            }
            if (j < e) a += Y[(size_t)eidx[j] * HD + lane];
            a = fmaxf(a + bp, 0.f);
        }
        Xs[r][lane] = a;
    }
    __syncthreads();

    const int rbase = wid * 16;
    float acc[16];
#pragma unroll
    for (int r = 0; r < 16; ++r) acc[r] = 0.f;

#pragma unroll 1
    for (int k0 = 0; k0 < HD; k0 += 8) {
        float wreg[8];
#pragma unroll
        for (int j = 0; j < 8; ++j) wreg[j] = Ws1[k0 + j][lane];
#pragma unroll
        for (int r = 0; r < 16; ++r) {
            const float4 x0 = *(const float4*)&Xs[rbase + r][k0 + 0];
            const float4 x1 = *(const float4*)&Xs[rbase + r][k0 + 4];
            float a = acc[r];
            a = fmaf(wreg[0], x0.x, a);
            a = fmaf(wreg[1], x0.y, a);
            a = fmaf(wreg[2], x0.z, a);
            a = fmaf(wreg[3], x0.w, a);
            a = fmaf(wreg[4], x1.x, a);
            a = fmaf(wreg[5], x1.y, a);
            a = fmaf(wreg[6], x1.z, a);
            a = fmaf(wreg[7], x1.w, a);
            acc[r] = a;
        }
    }

    // h2 = relu(acc + bb); pool over the wave's 16 consecutive rows
    const float bbv = bb[lane];
    const int vbase = row0 + rbase;
    int   curg = -1;
    float racc = 0.f;
    float rcnt = 0.f;
#pragma unroll
    for (int r = 0; r < 16; ++r) {
        const int v = vbase + r;
        int g = -1;
        if (v < n) g = batch[v];               // wave-uniform
        if (g != curg) {
            if (curg >= 0) {
                unsafeAtomicAdd(&sums[(size_t)curg * HD + lane], racc);
                if (lane == 0) unsafeAtomicAdd(&counts[curg], rcnt);
            }
            curg = g;
            racc = 0.f;
            rcnt = 0.f;
        }
        if (g >= 0) {
            racc += fmaxf(acc[r] + bbv, 0.f);
            rcnt += 1.f;
        }
    }
    if (curg >= 0) {
        unsafeAtomicAdd(&sums[(size_t)curg * HD + lane], racc);
        if (lane == 0) unsafeAtomicAdd(&counts[curg], rcnt);
    }
}

// ---------------------------------------------------------------------------
// out[g][c] = (sums[g][:]/max(counts[g],1)) . Wf[:][c] + bf[c]
// ---------------------------------------------------------------------------
__global__ __launch_bounds__(256) void final_linear(const float* __restrict__ sums,
                                                    const float* __restrict__ counts,
                                                    const float* __restrict__ Wf,
                                                    const float* __restrict__ bfv,
                                                    float* __restrict__ out, int G, int C) {
    const int t = blockIdx.x * 256 + threadIdx.x;
    if (t >= G * C) return;
    const int g = t / C;
    const int c = t - g * C;
    const float inv = 1.0f / fmaxf(counts[g], 1.0f);
    float acc = 0.f;
    for (int h = 0; h < HD; ++h) acc += sums[(size_t)g * HD + h] * Wf[h * C + c];
    out[t] = acc * inv + bfv[c];
}

extern "C" void kernel_launch(void* const* d_in, const int* in_sizes, int n_in,
                              void* d_out, int out_size, void* d_ws, size_t ws_size,
                              hipStream_t stream) {
    const float* x    = (const float*)d_in[0];
    const int*   ei   = (const int*)d_in[1];
    const int*   batc = (const int*)d_in[2];
    const float* W1a  = (const float*)d_in[3];
    const float* b1a  = (const float*)d_in[4];
    const float* W1b  = (const float*)d_in[5];
    const float* b1b  = (const float*)d_in[6];
    const float* W2a  = (const float*)d_in[7];
    const float* b2a  = (const float*)d_in[8];
    const float* W2b  = (const float*)d_in[9];
    const float* b2b  = (const float*)d_in[10];
    const float* Wf   = (const float*)d_in[11];
    const float* bfv  = (const float*)d_in[12];

    const int n = in_sizes[2];       // 100000 nodes
    const int E = in_sizes[1] / 2;   // 1M edges
    const int C = in_sizes[12];      // 2 classes
    const int G = out_size / C;      // 1000 graphs

    const int* src = ei;
    const int* dst = ei + E;

    float* bufA   = (float*)d_ws;                  // n x 64  (y1)
    float* bufB   = bufA + (size_t)n * HD;         // n x 64  (y2)
    float* sums   = bufB + (size_t)n * HD;         // G x 64
    float* counts = sums + (size_t)G * HD;         // G
    int*   deg    = (int*)(counts + G);            // n
    int*   start  = deg + n;                       // n
    int*   fillp  = start + n;                     // n (== end after fill)
    int*   cursor = fillp + n;                     // 1
    int*   eidx   = cursor + 1;                    // E

    const int gemmGrid = (n + 63) / 64;
    const int eGrid    = (E + 255) / 256;

    // ---- CSR build (once, reused by both layers)
    hipMemsetAsync(deg, 0, (size_t)n * sizeof(int), stream);
    hipMemsetAsync(cursor, 0, sizeof(int), stream);
    count_deg<<<eGrid, 256, 0, stream>>>(dst, deg, E);
    assign_starts<<<(n + 1023) / 1024, 256, 0, stream>>>(deg, start, fillp, cursor, n);
    fill_csr<<<eGrid, 256, 0, stream>>>(src, dst, fillp, eidx, E);

    // ---- y1 = x@W1a
    gemm_k<128><<<gemmGrid, 256, 0, stream>>>(x, W1a, bufA, n);

    // ---- Fused layer 1 + start of layer 2: y2 = relu(relu(y1+agg1+b1a)@W1b+b1b)@W2a
    layer_mid<<<gemmGrid, 256, 0, stream>>>(bufA, start, fillp, eidx,
                                            b1a, W1b, b1b, W2a, bufB, n);

    // ---- Fused layer 2 tail + pooling (h2 never hits HBM)
    hipMemsetAsync(sums, 0, (size_t)G * (HD + 1) * sizeof(float), stream);
    layer_end<<<gemmGrid, 256, 0, stream>>>(bufB, start, fillp, eidx,
                                            b2a, W2b, b2b, batc, sums, counts, n);

    // ---- Final linear
    final_linear<<<(G * C + 255) / 256, 256, 0, stream>>>(sums, counts, Wf, bfv,
                                                          (float*)d_out, G, C);
}

// Round 5
// 356.083 us; speedup vs baseline: 1.5000x; 1.5000x over previous
//
#include <hip/hip_runtime.h>

#define HD 64  // hidden dim

// ---------------------------------------------------------------------------
// Round-5 design: ALL heavy kernels are barrier-free. Each wave owns 16 rows
// (gathers them, computes on them, stores them) -> no cross-wave LDS sharing.
// W matrices are read from global (16 KB, L1/L2-resident broadcast) instead of
// LDS (round-4 lesson: 48 KB LDS -> 25% occupancy strangled the latency-bound
// gather phase; LDS is now Xs only = 16 KB, occupancy VGPR-bound ~28 waves/CU).
// k-loop kept at "#pragma unroll 1" chunks of 8 (round-1 lesson: full unroll
// -> 256 VGPR + 3.7 GB spill traffic).
// ---------------------------------------------------------------------------

// GEMM: Y[n x 64] = X[n x K] @ W[K x 64]   (the F=128 input GEMM)
template <int K>
__global__ __launch_bounds__(256) void gemm_k(const float* __restrict__ X,
                                              const float* __restrict__ W,
                                              float* __restrict__ Y, int n) {
    __shared__ float Xs[64][K];   // 32 KB for K=128; wave-private 16-row slices

    const int lane  = threadIdx.x & 63;
    const int wid   = threadIdx.x >> 6;
    const int row0  = blockIdx.x * 64;
    const int rbase = wid * 16;

    // stage this wave's 16 rows (float4, coalesced); no barrier needed
    {
        const int rowf4 = K / 4;
        const float4* Xg = (const float4*)X;
        for (int i = lane; i < 16 * rowf4; i += 64) {
            const int r   = i / rowf4;
            const int c4  = i - r * rowf4;
            const int row = row0 + rbase + r;
            float4 v = make_float4(0.f, 0.f, 0.f, 0.f);
            if (row < n) v = Xg[(size_t)row * rowf4 + c4];
            *(float4*)&Xs[rbase + r][c4 * 4] = v;
        }
    }

    float acc[16];
#pragma unroll
    for (int r = 0; r < 16; ++r) acc[r] = 0.f;

#pragma unroll 1
    for (int k0 = 0; k0 < K; k0 += 8) {
        float wreg[8];
#pragma unroll
        for (int j = 0; j < 8; ++j) wreg[j] = W[(k0 + j) * HD + lane];
#pragma unroll
        for (int r = 0; r < 16; ++r) {
            const float4 x0 = *(const float4*)&Xs[rbase + r][k0 + 0];
            const float4 x1 = *(const float4*)&Xs[rbase + r][k0 + 4];
            float a = acc[r];
            a = fmaf(wreg[0], x0.x, a);
            a = fmaf(wreg[1], x0.y, a);
            a = fmaf(wreg[2], x0.z, a);
            a = fmaf(wreg[3], x0.w, a);
            a = fmaf(wreg[4], x1.x, a);
            a = fmaf(wreg[5], x1.y, a);
            a = fmaf(wreg[6], x1.z, a);
            a = fmaf(wreg[7], x1.w, a);
            acc[r] = a;
        }
    }

#pragma unroll
    for (int r = 0; r < 16; ++r) {
        const int row = row0 + rbase + r;
        if (row < n) Y[(size_t)row * HD + lane] = acc[r];
    }
}

// ---------------------------------------------------------------------------
// CSR build (round-2 lesson: 64M fp32 atomics = 850 us/pass; int-ticket CSR
// + gather is ~10x cheaper). Fill order nondeterministic; slot ranges are
// contiguous per node regardless of order.
// ---------------------------------------------------------------------------
__global__ __launch_bounds__(256) void count_deg(const int* __restrict__ dst,
                                                 int* __restrict__ deg, int E) {
    const int t = blockIdx.x * 256 + threadIdx.x;
    if (t < E) atomicAdd(&deg[dst[t]], 1);
}

__global__ __launch_bounds__(256) void assign_starts(const int* __restrict__ deg,
                                                     int* __restrict__ start,
                                                     int* __restrict__ fillpos,
                                                     int* __restrict__ cursor, int n) {
    const int t     = blockIdx.x * 256 + threadIdx.x;
    const int lane  = threadIdx.x & 63;
    const int base4 = t * 4;
    int d[4];
    int tot = 0;
#pragma unroll
    for (int i = 0; i < 4; ++i) {
        d[i] = (base4 + i < n) ? deg[base4 + i] : 0;
        tot += d[i];
    }
    int pfx = tot;
#pragma unroll
    for (int off = 1; off < 64; off <<= 1) {
        const int y = __shfl_up(pfx, off);
        if (lane >= off) pfx += y;
    }
    const int excl = pfx - tot;
    int base = 0;
    if (lane == 63) base = atomicAdd(cursor, pfx);
    base = __shfl(base, 63);
    int s = base + excl;
#pragma unroll
    for (int i = 0; i < 4; ++i) {
        if (base4 + i < n) {
            start[base4 + i]   = s;
            fillpos[base4 + i] = s;
        }
        s += d[i];
    }
}

__global__ __launch_bounds__(256) void fill_csr(const int* __restrict__ src,
                                                const int* __restrict__ dst,
                                                int* __restrict__ fillpos,
                                                int* __restrict__ eidx, int E) {
    const int t = blockIdx.x * 256 + threadIdx.x;
    if (t < E) {
        const int p = atomicAdd(&fillpos[dst[t]], 1);
        eidx[p] = src[t];
    }
}

// ---------------------------------------------------------------------------
// Fused GIN layer (middle), barrier-free:
//   per wave, rows rbase..rbase+15:
//     t  = relu(y1[v] + sum_{u in N(v)} y1[u] + bpre)  -> Xs (own rows)
//     h1 = relu(t@Wb + bb)                             -> Xs (own rows)
//     y2 = h1@Wn                                       -> HBM
// agg and h1 never touch HBM.
// ---------------------------------------------------------------------------
__global__ __launch_bounds__(256) void layer_mid(const float* __restrict__ Y,
                                                 const int* __restrict__ start,
                                                 const int* __restrict__ endp,
                                                 const int* __restrict__ eidx,
                                                 const float* __restrict__ bpre,
                                                 const float* __restrict__ Wb,
                                                 const float* __restrict__ bb,
                                                 const float* __restrict__ Wn,
                                                 float* __restrict__ Yout, int n) {
    __shared__ float Xs[64][HD];  // 16 KB

    const int lane  = threadIdx.x & 63;
    const int wid   = threadIdx.x >> 6;
    const int row0  = blockIdx.x * 64;
    const int rbase = wid * 16;

    // gather-PRE: this wave's 16 rows; lane = column
    const float bp = bpre[lane];
#pragma unroll 1
    for (int r = 0; r < 16; ++r) {
        const int v = row0 + rbase + r;
        float a = 0.f;
        if (v < n) {
            a = Y[(size_t)v * HD + lane];
            const int s = start[v];
            const int e = endp[v];
            int j = s;
            for (; j + 1 < e; j += 2) {
                const int u0 = eidx[j];
                const int u1 = eidx[j + 1];
                a += Y[(size_t)u0 * HD + lane] + Y[(size_t)u1 * HD + lane];
            }
            if (j < e) a += Y[(size_t)eidx[j] * HD + lane];
            a = fmaxf(a + bp, 0.f);
        }
        Xs[rbase + r][lane] = a;
    }

    float acc[16];
#pragma unroll
    for (int r = 0; r < 16; ++r) acc[r] = 0.f;

#pragma unroll 1
    for (int k0 = 0; k0 < HD; k0 += 8) {
        float wreg[8];
#pragma unroll
        for (int j = 0; j < 8; ++j) wreg[j] = Wb[(k0 + j) * HD + lane];
#pragma unroll
        for (int r = 0; r < 16; ++r) {
            const float4 x0 = *(const float4*)&Xs[rbase + r][k0 + 0];
            const float4 x1 = *(const float4*)&Xs[rbase + r][k0 + 4];
            float a = acc[r];
            a = fmaf(wreg[0], x0.x, a);
            a = fmaf(wreg[1], x0.y, a);
            a = fmaf(wreg[2], x0.z, a);
            a = fmaf(wreg[3], x0.w, a);
            a = fmaf(wreg[4], x1.x, a);
            a = fmaf(wreg[5], x1.y, a);
            a = fmaf(wreg[6], x1.z, a);
            a = fmaf(wreg[7], x1.w, a);
            acc[r] = a;
        }
    }

    // h1 back into the wave's own rows (in-wave ds ordering handled by lgkmcnt)
    const float bbv = bb[lane];
#pragma unroll
    for (int r = 0; r < 16; ++r) Xs[rbase + r][lane] = fmaxf(acc[r] + bbv, 0.f);

    float acc2[16];
#pragma unroll
    for (int r = 0; r < 16; ++r) acc2[r] = 0.f;

#pragma unroll 1
    for (int k0 = 0; k0 < HD; k0 += 8) {
        float wreg[8];
#pragma unroll
        for (int j = 0; j < 8; ++j) wreg[j] = Wn[(k0 + j) * HD + lane];
#pragma unroll
        for (int r = 0; r < 16; ++r) {
            const float4 x0 = *(const float4*)&Xs[rbase + r][k0 + 0];
            const float4 x1 = *(const float4*)&Xs[rbase + r][k0 + 4];
            float a = acc2[r];
            a = fmaf(wreg[0], x0.x, a);
            a = fmaf(wreg[1], x0.y, a);
            a = fmaf(wreg[2], x0.z, a);
            a = fmaf(wreg[3], x0.w, a);
            a = fmaf(wreg[4], x1.x, a);
            a = fmaf(wreg[5], x1.y, a);
            a = fmaf(wreg[6], x1.z, a);
            a = fmaf(wreg[7], x1.w, a);
            acc2[r] = a;
        }
    }

#pragma unroll
    for (int r = 0; r < 16; ++r) {
        const int row = row0 + rbase + r;
        if (row < n) Yout[(size_t)row * HD + lane] = acc2[r];
    }
}

// ---------------------------------------------------------------------------
// Fused GIN layer (final), barrier-free: h2 = relu(t2@Wb+bb) in registers,
// pooled directly (batch sorted -> run-accumulate over the wave's 16
// consecutive rows, one atomic row per run). h2 never written to HBM.
// ---------------------------------------------------------------------------
__global__ __launch_bounds__(256) void layer_end(const float* __restrict__ Y,
                                                 const int* __restrict__ start,
                                                 const int* __restrict__ endp,
                                                 const int* __restrict__ eidx,
                                                 const float* __restrict__ bpre,
                                                 const float* __restrict__ Wb,
                                                 const float* __restrict__ bb,
                                                 const int* __restrict__ batch,
                                                 float* __restrict__ sums,
                                                 float* __restrict__ counts, int n) {
    __shared__ float Xs[64][HD];  // 16 KB

    const int lane  = threadIdx.x & 63;
    const int wid   = threadIdx.x >> 6;
    const int row0  = blockIdx.x * 64;
    const int rbase = wid * 16;

    const float bp = bpre[lane];
#pragma unroll 1
    for (int r = 0; r < 16; ++r) {
        const int v = row0 + rbase + r;
        float a = 0.f;
        if (v < n) {
            a = Y[(size_t)v * HD + lane];
            const int s = start[v];
            const int e = endp[v];
            int j = s;
            for (; j + 1 < e; j += 2) {
                const int u0 = eidx[j];
                const int u1 = eidx[j + 1];
                a += Y[(size_t)u0 * HD + lane] + Y[(size_t)u1 * HD + lane];
            }
            if (j < e) a += Y[(size_t)eidx[j] * HD + lane];
            a = fmaxf(a + bp, 0.f);
        }
        Xs[rbase + r][lane] = a;
    }

    float acc[16];
#pragma unroll
    for (int r = 0; r < 16; ++r) acc[r] = 0.f;

#pragma unroll 1
    for (int k0 = 0; k0 < HD; k0 += 8) {
        float wreg[8];
#pragma unroll
        for (int j = 0; j < 8; ++j) wreg[j] = Wb[(k0 + j) * HD + lane];
#pragma unroll
        for (int r = 0; r < 16; ++r) {
            const float4 x0 = *(const float4*)&Xs[rbase + r][k0 + 0];
            const float4 x1 = *(const float4*)&Xs[rbase + r][k0 + 4];
            float a = acc[r];
            a = fmaf(wreg[0], x0.x, a);
            a = fmaf(wreg[1], x0.y, a);
            a = fmaf(wreg[2], x0.z, a);
            a = fmaf(wreg[3], x0.w, a);
            a = fmaf(wreg[4], x1.x, a);
            a = fmaf(wreg[5], x1.y, a);
            a = fmaf(wreg[6], x1.z, a);
            a = fmaf(wreg[7], x1.w, a);
            acc[r] = a;
        }
    }

    // h2 = relu(acc + bb); pool over the wave's 16 consecutive rows
    const float bbv = bb[lane];
    const int vbase = row0 + rbase;
    int   curg = -1;
    float racc = 0.f;
    float rcnt = 0.f;
#pragma unroll
    for (int r = 0; r < 16; ++r) {
        const int v = vbase + r;
        int g = -1;
        if (v < n) g = batch[v];               // wave-uniform
        if (g != curg) {
            if (curg >= 0) {
                unsafeAtomicAdd(&sums[(size_t)curg * HD + lane], racc);
                if (lane == 0) unsafeAtomicAdd(&counts[curg], rcnt);
            }
            curg = g;
            racc = 0.f;
            rcnt = 0.f;
        }
        if (g >= 0) {
            racc += fmaxf(acc[r] + bbv, 0.f);
            rcnt += 1.f;
        }
    }
    if (curg >= 0) {
        unsafeAtomicAdd(&sums[(size_t)curg * HD + lane], racc);
        if (lane == 0) unsafeAtomicAdd(&counts[curg], rcnt);
    }
}

// ---------------------------------------------------------------------------
// out[g][c] = (sums[g][:]/max(counts[g],1)) . Wf[:][c] + bf[c]
// ---------------------------------------------------------------------------
__global__ __launch_bounds__(256) void final_linear(const float* __restrict__ sums,
                                                    const float* __restrict__ counts,
                                                    const float* __restrict__ Wf,
                                                    const float* __restrict__ bfv,
                                                    float* __restrict__ out, int G, int C) {
    const int t = blockIdx.x * 256 + threadIdx.x;
    if (t >= G * C) return;
    const int g = t / C;
    const int c = t - g * C;
    const float inv = 1.0f / fmaxf(counts[g], 1.0f);
    float acc = 0.f;
    for (int h = 0; h < HD; ++h) acc += sums[(size_t)g * HD + h] * Wf[h * C + c];
    out[t] = acc * inv + bfv[c];
}

extern "C" void kernel_launch(void* const* d_in, const int* in_sizes, int n_in,
                              void* d_out, int out_size, void* d_ws, size_t ws_size,
                              hipStream_t stream) {
    const float* x    = (const float*)d_in[0];
    const int*   ei   = (const int*)d_in[1];
    const int*   batc = (const int*)d_in[2];
    const float* W1a  = (const float*)d_in[3];
    const float* b1a  = (const float*)d_in[4];
    const float* W1b  = (const float*)d_in[5];
    const float* b1b  = (const float*)d_in[6];
    const float* W2a  = (const float*)d_in[7];
    const float* b2a  = (const float*)d_in[8];
    const float* W2b  = (const float*)d_in[9];
    const float* b2b  = (const float*)d_in[10];
    const float* Wf   = (const float*)d_in[11];
    const float* bfv  = (const float*)d_in[12];

    const int n = in_sizes[2];       // 100000 nodes
    const int E = in_sizes[1] / 2;   // 1M edges
    const int C = in_sizes[12];      // 2 classes
    const int G = out_size / C;      // 1000 graphs

    const int* src = ei;
    const int* dst = ei + E;

    float* bufA   = (float*)d_ws;                  // n x 64  (y1)
    float* bufB   = bufA + (size_t)n * HD;         // n x 64  (y2)
    float* sums   = bufB + (size_t)n * HD;         // G x 64
    float* counts = sums + (size_t)G * HD;         // G
    int*   deg    = (int*)(counts + G);            // n
    int*   start  = deg + n;                       // n
    int*   fillp  = start + n;                     // n (== end after fill)
    int*   cursor = fillp + n;                     // 1
    int*   eidx   = cursor + 1;                    // E

    const int gemmGrid = (n + 63) / 64;
    const int eGrid    = (E + 255) / 256;

    // ---- CSR build (once, reused by both layers)
    hipMemsetAsync(deg, 0, (size_t)n * sizeof(int), stream);
    hipMemsetAsync(cursor, 0, sizeof(int), stream);
    count_deg<<<eGrid, 256, 0, stream>>>(dst, deg, E);
    assign_starts<<<(n + 1023) / 1024, 256, 0, stream>>>(deg, start, fillp, cursor, n);
    fill_csr<<<eGrid, 256, 0, stream>>>(src, dst, fillp, eidx, E);

    // ---- y1 = x@W1a
    gemm_k<128><<<gemmGrid, 256, 0, stream>>>(x, W1a, bufA, n);

    // ---- Fused layer 1 + start of layer 2: y2 = relu(relu(y1+agg1+b1a)@W1b+b1b)@W2a
    layer_mid<<<gemmGrid, 256, 0, stream>>>(bufA, start, fillp, eidx,
                                            b1a, W1b, b1b, W2a, bufB, n);

    // ---- Fused layer 2 tail + pooling (h2 never hits HBM)
    hipMemsetAsync(sums, 0, (size_t)G * (HD + 1) * sizeof(float), stream);
    layer_end<<<gemmGrid, 256, 0, stream>>>(bufB, start, fillp, eidx,
                                            b2a, W2b, b2b, batc, sums, counts, n);

    // ---- Final linear
    final_linear<<<(G * C + 255) / 256, 256, 0, stream>>>(sums, counts, Wf, bfv,
                                                          (float*)d_out, G, C);
}

// Round 6
// 317.699 us; speedup vs baseline: 1.6813x; 1.1208x over previous
//
#include <hip/hip_runtime.h>

#define HD 64  // hidden dim

// ---------------------------------------------------------------------------
// Round-6 design notes (carrying forward hard-won lessons):
//  - r1: never fully unroll the k-loop (256 VGPR + 3.7 GB spill). Chunks of 8.
//  - r2: no fp32 atomic scatter over edges (64M atomics = 850 us/pass).
//  - r4: keep LDS tiny + barrier-free; the gather phase is latency-bound and
//        needs occupancy (48 KB LDS / barriers => 25% occ, 2x regression).
//  - r6 (new): gather indices via ONE coalesced eidx load + __shfl broadcast
//        (kills the per-edge dependent index load), row loads issued in
//        batches of 8 for MLP; 2-wave blocks for scheduling granularity.
// ---------------------------------------------------------------------------

// GEMM: Y[n x 64] = X[n x K] @ W[K x 64]   (the F=128 input GEMM)
template <int K>
__global__ __launch_bounds__(256) void gemm_k(const float* __restrict__ X,
                                              const float* __restrict__ W,
                                              float* __restrict__ Y, int n) {
    __shared__ float Xs[64][K];   // wave-private 16-row slices

    const int lane  = threadIdx.x & 63;
    const int wid   = threadIdx.x >> 6;
    const int row0  = blockIdx.x * 64;
    const int rbase = wid * 16;

    {
        const int rowf4 = K / 4;
        const float4* Xg = (const float4*)X;
        for (int i = lane; i < 16 * rowf4; i += 64) {
            const int r   = i / rowf4;
            const int c4  = i - r * rowf4;
            const int row = row0 + rbase + r;
            float4 v = make_float4(0.f, 0.f, 0.f, 0.f);
            if (row < n) v = Xg[(size_t)row * rowf4 + c4];
            *(float4*)&Xs[rbase + r][c4 * 4] = v;
        }
    }

    float acc[16];
#pragma unroll
    for (int r = 0; r < 16; ++r) acc[r] = 0.f;

#pragma unroll 1
    for (int k0 = 0; k0 < K; k0 += 8) {
        float wreg[8];
#pragma unroll
        for (int j = 0; j < 8; ++j) wreg[j] = W[(k0 + j) * HD + lane];
#pragma unroll
        for (int r = 0; r < 16; ++r) {
            const float4 x0 = *(const float4*)&Xs[rbase + r][k0 + 0];
            const float4 x1 = *(const float4*)&Xs[rbase + r][k0 + 4];
            float a = acc[r];
            a = fmaf(wreg[0], x0.x, a);
            a = fmaf(wreg[1], x0.y, a);
            a = fmaf(wreg[2], x0.z, a);
            a = fmaf(wreg[3], x0.w, a);
            a = fmaf(wreg[4], x1.x, a);
            a = fmaf(wreg[5], x1.y, a);
            a = fmaf(wreg[6], x1.z, a);
            a = fmaf(wreg[7], x1.w, a);
            acc[r] = a;
        }
    }

#pragma unroll
    for (int r = 0; r < 16; ++r) {
        const int row = row0 + rbase + r;
        if (row < n) Y[(size_t)row * HD + lane] = acc[r];
    }
}

// ---------------------------------------------------------------------------
// CSR build
// ---------------------------------------------------------------------------
__global__ __launch_bounds__(256) void count_deg(const int* __restrict__ dst,
                                                 int* __restrict__ deg, int E) {
    const int t = blockIdx.x * 256 + threadIdx.x;
    if (t < E) atomicAdd(&deg[dst[t]], 1);
}

__global__ __launch_bounds__(256) void assign_starts(const int* __restrict__ deg,
                                                     int* __restrict__ start,
                                                     int* __restrict__ fillpos,
                                                     int* __restrict__ cursor, int n) {
    const int t     = blockIdx.x * 256 + threadIdx.x;
    const int lane  = threadIdx.x & 63;
    const int base4 = t * 4;
    int d[4];
    int tot = 0;
#pragma unroll
    for (int i = 0; i < 4; ++i) {
        d[i] = (base4 + i < n) ? deg[base4 + i] : 0;
        tot += d[i];
    }
    int pfx = tot;
#pragma unroll
    for (int off = 1; off < 64; off <<= 1) {
        const int y = __shfl_up(pfx, off);
        if (lane >= off) pfx += y;
    }
    const int excl = pfx - tot;
    int base = 0;
    if (lane == 63) base = atomicAdd(cursor, pfx);
    base = __shfl(base, 63);
    int s = base + excl;
#pragma unroll
    for (int i = 0; i < 4; ++i) {
        if (base4 + i < n) {
            start[base4 + i]   = s;
            fillpos[base4 + i] = s;
        }
        s += d[i];
    }
}

__global__ __launch_bounds__(256) void fill_csr(const int* __restrict__ src,
                                                const int* __restrict__ dst,
                                                int* __restrict__ fillpos,
                                                int* __restrict__ eidx, int E) {
    const int t = blockIdx.x * 256 + threadIdx.x;
    if (t < E) {
        const int p = atomicAdd(&fillpos[dst[t]], 1);
        eidx[p] = src[t];
    }
}

// ---------------------------------------------------------------------------
// Gather for one row (node v): a = Y[v] + sum_{u in N(v)} Y[u]  (column=lane).
// Indices fetched 64-at-a-time via ONE coalesced load + __shfl broadcast;
// row loads issued in batches of 8/4/2/1 for MLP.
// ---------------------------------------------------------------------------
__device__ __forceinline__ float gather_row(const float* __restrict__ Y,
                                            const int* __restrict__ eidx,
                                            int s, int e, int v, int lane) {
    float a = Y[(size_t)v * HD + lane];
    int base = s;
    while (base < e) {
        const int chunk = min(64, e - base);
        const int myu = (lane < chunk) ? eidx[base + lane] : 0;
        int i = 0;
        for (; i + 7 < chunk; i += 8) {
            const int u0 = __shfl(myu, i + 0);
            const int u1 = __shfl(myu, i + 1);
            const int u2 = __shfl(myu, i + 2);
            const int u3 = __shfl(myu, i + 3);
            const int u4 = __shfl(myu, i + 4);
            const int u5 = __shfl(myu, i + 5);
            const int u6 = __shfl(myu, i + 6);
            const int u7 = __shfl(myu, i + 7);
            const float f0 = Y[(size_t)u0 * HD + lane];
            const float f1 = Y[(size_t)u1 * HD + lane];
            const float f2 = Y[(size_t)u2 * HD + lane];
            const float f3 = Y[(size_t)u3 * HD + lane];
            const float f4 = Y[(size_t)u4 * HD + lane];
            const float f5 = Y[(size_t)u5 * HD + lane];
            const float f6 = Y[(size_t)u6 * HD + lane];
            const float f7 = Y[(size_t)u7 * HD + lane];
            a += ((f0 + f1) + (f2 + f3)) + ((f4 + f5) + (f6 + f7));
        }
        if (i + 3 < chunk) {
            const int u0 = __shfl(myu, i + 0);
            const int u1 = __shfl(myu, i + 1);
            const int u2 = __shfl(myu, i + 2);
            const int u3 = __shfl(myu, i + 3);
            const float f0 = Y[(size_t)u0 * HD + lane];
            const float f1 = Y[(size_t)u1 * HD + lane];
            const float f2 = Y[(size_t)u2 * HD + lane];
            const float f3 = Y[(size_t)u3 * HD + lane];
            a += (f0 + f1) + (f2 + f3);
            i += 4;
        }
        if (i + 1 < chunk) {
            const int u0 = __shfl(myu, i + 0);
            const int u1 = __shfl(myu, i + 1);
            a += Y[(size_t)u0 * HD + lane] + Y[(size_t)u1 * HD + lane];
            i += 2;
        }
        if (i < chunk) {
            const int u0 = __shfl(myu, i);
            a += Y[(size_t)u0 * HD + lane];
        }
        base += chunk;
    }
    return a;
}

// ---------------------------------------------------------------------------
// Fused GIN layer (middle), barrier-free, 2-wave blocks (32 rows):
//   t = relu(gather + bpre) -> Xs ; h1 = relu(t@Wb+bb) -> Xs ; y2 = h1@Wn -> HBM
// ---------------------------------------------------------------------------
__global__ __launch_bounds__(128) void layer_mid(const float* __restrict__ Y,
                                                 const int* __restrict__ start,
                                                 const int* __restrict__ endp,
                                                 const int* __restrict__ eidx,
                                                 const float* __restrict__ bpre,
                                                 const float* __restrict__ Wb,
                                                 const float* __restrict__ bb,
                                                 const float* __restrict__ Wn,
                                                 float* __restrict__ Yout, int n) {
    __shared__ float Xs[32][HD];  // 8 KB

    const int lane  = threadIdx.x & 63;
    const int wid   = threadIdx.x >> 6;   // 0..1
    const int row0  = blockIdx.x * 32;
    const int rbase = wid * 16;

    const float bp = bpre[lane];
#pragma unroll 1
    for (int r = 0; r < 16; ++r) {
        const int v = row0 + rbase + r;
        float a = 0.f;
        if (v < n) {
            a = gather_row(Y, eidx, start[v], endp[v], v, lane);
            a = fmaxf(a + bp, 0.f);
        }
        Xs[rbase + r][lane] = a;
    }

    float acc[16];
#pragma unroll
    for (int r = 0; r < 16; ++r) acc[r] = 0.f;

#pragma unroll 1
    for (int k0 = 0; k0 < HD; k0 += 8) {
        float wreg[8];
#pragma unroll
        for (int j = 0; j < 8; ++j) wreg[j] = Wb[(k0 + j) * HD + lane];
#pragma unroll
        for (int r = 0; r < 16; ++r) {
            const float4 x0 = *(const float4*)&Xs[rbase + r][k0 + 0];
            const float4 x1 = *(const float4*)&Xs[rbase + r][k0 + 4];
            float a = acc[r];
            a = fmaf(wreg[0], x0.x, a);
            a = fmaf(wreg[1], x0.y, a);
            a = fmaf(wreg[2], x0.z, a);
            a = fmaf(wreg[3], x0.w, a);
            a = fmaf(wreg[4], x1.x, a);
            a = fmaf(wreg[5], x1.y, a);
            a = fmaf(wreg[6], x1.z, a);
            a = fmaf(wreg[7], x1.w, a);
            acc[r] = a;
        }
    }

    const float bbv = bb[lane];
#pragma unroll
    for (int r = 0; r < 16; ++r) Xs[rbase + r][lane] = fmaxf(acc[r] + bbv, 0.f);

    float acc2[16];
#pragma unroll
    for (int r = 0; r < 16; ++r) acc2[r] = 0.f;

#pragma unroll 1
    for (int k0 = 0; k0 < HD; k0 += 8) {
        float wreg[8];
#pragma unroll
        for (int j = 0; j < 8; ++j) wreg[j] = Wn[(k0 + j) * HD + lane];
#pragma unroll
        for (int r = 0; r < 16; ++r) {
            const float4 x0 = *(const float4*)&Xs[rbase + r][k0 + 0];
            const float4 x1 = *(const float4*)&Xs[rbase + r][k0 + 4];
            float a = acc2[r];
            a = fmaf(wreg[0], x0.x, a);
            a = fmaf(wreg[1], x0.y, a);
            a = fmaf(wreg[2], x0.z, a);
            a = fmaf(wreg[3], x0.w, a);
            a = fmaf(wreg[4], x1.x, a);
            a = fmaf(wreg[5], x1.y, a);
            a = fmaf(wreg[6], x1.z, a);
            a = fmaf(wreg[7], x1.w, a);
            acc2[r] = a;
        }
    }

#pragma unroll
    for (int r = 0; r < 16; ++r) {
        const int row = row0 + rbase + r;
        if (row < n) Yout[(size_t)row * HD + lane] = acc2[r];
    }
}

// ---------------------------------------------------------------------------
// Fused GIN layer (final) + pooling, barrier-free, 2-wave blocks.
// ---------------------------------------------------------------------------
__global__ __launch_bounds__(128) void layer_end(const float* __restrict__ Y,
                                                 const int* __restrict__ start,
                                                 const int* __restrict__ endp,
                                                 const int* __restrict__ eidx,
                                                 const float* __restrict__ bpre,
                                                 const float* __restrict__ Wb,
                                                 const float* __restrict__ bb,
                                                 const int* __restrict__ batch,
                                                 float* __restrict__ sums,
                                                 float* __restrict__ counts, int n) {
    __shared__ float Xs[32][HD];  // 8 KB

    const int lane  = threadIdx.x & 63;
    const int wid   = threadIdx.x >> 6;
    const int row0  = blockIdx.x * 32;
    const int rbase = wid * 16;

    const float bp = bpre[lane];
#pragma unroll 1
    for (int r = 0; r < 16; ++r) {
        const int v = row0 + rbase + r;
        float a = 0.f;
        if (v < n) {
            a = gather_row(Y, eidx, start[v], endp[v], v, lane);
            a = fmaxf(a + bp, 0.f);
        }
        Xs[rbase + r][lane] = a;
    }

    float acc[16];
#pragma unroll
    for (int r = 0; r < 16; ++r) acc[r] = 0.f;

#pragma unroll 1
    for (int k0 = 0; k0 < HD; k0 += 8) {
        float wreg[8];
#pragma unroll
        for (int j = 0; j < 8; ++j) wreg[j] = Wb[(k0 + j) * HD + lane];
#pragma unroll
        for (int r = 0; r < 16; ++r) {
            const float4 x0 = *(const float4*)&Xs[rbase + r][k0 + 0];
            const float4 x1 = *(const float4*)&Xs[rbase + r][k0 + 4];
            float a = acc[r];
            a = fmaf(wreg[0], x0.x, a);
            a = fmaf(wreg[1], x0.y, a);
            a = fmaf(wreg[2], x0.z, a);
            a = fmaf(wreg[3], x0.w, a);
            a = fmaf(wreg[4], x1.x, a);
            a = fmaf(wreg[5], x1.y, a);
            a = fmaf(wreg[6], x1.z, a);
            a = fmaf(wreg[7], x1.w, a);
            acc[r] = a;
        }
    }

    // h2 = relu(acc + bb); run-accumulate pool over 16 consecutive rows
    const float bbv = bb[lane];
    const int vbase = row0 + rbase;
    int   curg = -1;
    float racc = 0.f;
    float rcnt = 0.f;
#pragma unroll
    for (int r = 0; r < 16; ++r) {
        const int v = vbase + r;
        int g = -1;
        if (v < n) g = batch[v];               // wave-uniform
        if (g != curg) {
            if (curg >= 0) {
                unsafeAtomicAdd(&sums[(size_t)curg * HD + lane], racc);
                if (lane == 0) unsafeAtomicAdd(&counts[curg], rcnt);
            }
            curg = g;
            racc = 0.f;
            rcnt = 0.f;
        }
        if (g >= 0) {
            racc += fmaxf(acc[r] + bbv, 0.f);
            rcnt += 1.f;
        }
    }
    if (curg >= 0) {
        unsafeAtomicAdd(&sums[(size_t)curg * HD + lane], racc);
        if (lane == 0) unsafeAtomicAdd(&counts[curg], rcnt);
    }
}

// ---------------------------------------------------------------------------
// out[g][c] = (sums[g][:]/max(counts[g],1)) . Wf[:][c] + bf[c]
// ---------------------------------------------------------------------------
__global__ __launch_bounds__(256) void final_linear(const float* __restrict__ sums,
                                                    const float* __restrict__ counts,
                                                    const float* __restrict__ Wf,
                                                    const float* __restrict__ bfv,
                                                    float* __restrict__ out, int G, int C) {
    const int t = blockIdx.x * 256 + threadIdx.x;
    if (t >= G * C) return;
    const int g = t / C;
    const int c = t - g * C;
    const float inv = 1.0f / fmaxf(counts[g], 1.0f);
    float acc = 0.f;
    for (int h = 0; h < HD; ++h) acc += sums[(size_t)g * HD + h] * Wf[h * C + c];
    out[t] = acc * inv + bfv[c];
}

extern "C" void kernel_launch(void* const* d_in, const int* in_sizes, int n_in,
                              void* d_out, int out_size, void* d_ws, size_t ws_size,
                              hipStream_t stream) {
    const float* x    = (const float*)d_in[0];
    const int*   ei   = (const int*)d_in[1];
    const int*   batc = (const int*)d_in[2];
    const float* W1a  = (const float*)d_in[3];
    const float* b1a  = (const float*)d_in[4];
    const float* W1b  = (const float*)d_in[5];
    const float* b1b  = (const float*)d_in[6];
    const float* W2a  = (const float*)d_in[7];
    const float* b2a  = (const float*)d_in[8];
    const float* W2b  = (const float*)d_in[9];
    const float* b2b  = (const float*)d_in[10];
    const float* Wf   = (const float*)d_in[11];
    const float* bfv  = (const float*)d_in[12];

    const int n = in_sizes[2];       // 100000 nodes
    const int E = in_sizes[1] / 2;   // 1M edges
    const int C = in_sizes[12];      // 2 classes
    const int G = out_size / C;      // 1000 graphs

    const int* src = ei;
    const int* dst = ei + E;

    float* bufA   = (float*)d_ws;                  // n x 64  (y1)
    float* bufB   = bufA + (size_t)n * HD;         // n x 64  (y2)
    float* sums   = bufB + (size_t)n * HD;         // G x 64
    float* counts = sums + (size_t)G * HD;         // G
    int*   deg    = (int*)(counts + G);            // n
    int*   start  = deg + n;                       // n
    int*   fillp  = start + n;                     // n (== end after fill)
    int*   cursor = fillp + n;                     // 1
    int*   eidx   = cursor + 1;                    // E

    const int gemmGrid  = (n + 63) / 64;
    const int layerGrid = (n + 31) / 32;
    const int eGrid     = (E + 255) / 256;

    // ---- CSR build (once, reused by both layers)
    hipMemsetAsync(deg, 0, (size_t)n * sizeof(int), stream);
    hipMemsetAsync(cursor, 0, sizeof(int), stream);
    count_deg<<<eGrid, 256, 0, stream>>>(dst, deg, E);
    assign_starts<<<(n + 1023) / 1024, 256, 0, stream>>>(deg, start, fillp, cursor, n);
    fill_csr<<<eGrid, 256, 0, stream>>>(src, dst, fillp, eidx, E);

    // ---- y1 = x@W1a
    gemm_k<128><<<gemmGrid, 256, 0, stream>>>(x, W1a, bufA, n);

    // ---- Fused layer 1 + start of layer 2
    layer_mid<<<layerGrid, 128, 0, stream>>>(bufA, start, fillp, eidx,
                                             b1a, W1b, b1b, W2a, bufB, n);

    // ---- Fused layer 2 tail + pooling
    hipMemsetAsync(sums, 0, (size_t)G * (HD + 1) * sizeof(float), stream);
    layer_end<<<layerGrid, 128, 0, stream>>>(bufB, start, fillp, eidx,
                                             b2a, W2b, b2b, batc, sums, counts, n);

    // ---- Final linear
    final_linear<<<(G * C + 255) / 256, 256, 0, stream>>>(sums, counts, Wf, bfv,
                                                          (float*)d_out, G, C);
}

// Round 7
// 308.983 us; speedup vs baseline: 1.7287x; 1.0282x over previous
//
#include <hip/hip_runtime.h>

#define HD 64  // hidden dim

// ---------------------------------------------------------------------------
// Round-7 design notes (carrying forward hard-won lessons):
//  - r1: never fully unroll the k-loop (256 VGPR + 3.7 GB spill). Chunks of 8.
//  - r2: no fp32 atomic scatter over edges (64M atomics = 850 us/pass).
//  - r4: keep LDS tiny + barrier-free; gather is latency-bound, needs occupancy.
//  - r6: coalesced eidx load + cross-lane broadcast beats per-edge index loads.
//  - r7 (new): quad-gather — lane = (edge-subset, col-quad); one float4 load
//        fetches 4 rows/instr; 4 masked loads cover 16 edges with ~5 KB in
//        flight and ONE dependent-latency hop per node. Cross-subset
//        shfl_xor reduce (8+8 ops) restores lane=col layout.
// ---------------------------------------------------------------------------

// GEMM: Y[n x 64] = X[n x K] @ W[K x 64]   (the F=128 input GEMM)
template <int K>
__global__ __launch_bounds__(256) void gemm_k(const float* __restrict__ X,
                                              const float* __restrict__ W,
                                              float* __restrict__ Y, int n) {
    __shared__ float Xs[64][K];   // wave-private 16-row slices

    const int lane  = threadIdx.x & 63;
    const int wid   = threadIdx.x >> 6;
    const int row0  = blockIdx.x * 64;
    const int rbase = wid * 16;

    {
        const int rowf4 = K / 4;
        const float4* Xg = (const float4*)X;
        for (int i = lane; i < 16 * rowf4; i += 64) {
            const int r   = i / rowf4;
            const int c4  = i - r * rowf4;
            const int row = row0 + rbase + r;
            float4 v = make_float4(0.f, 0.f, 0.f, 0.f);
            if (row < n) v = Xg[(size_t)row * rowf4 + c4];
            *(float4*)&Xs[rbase + r][c4 * 4] = v;
        }
    }

    float acc[16];
#pragma unroll
    for (int r = 0; r < 16; ++r) acc[r] = 0.f;

#pragma unroll 1
    for (int k0 = 0; k0 < K; k0 += 8) {
        float wreg[8];
#pragma unroll
        for (int j = 0; j < 8; ++j) wreg[j] = W[(k0 + j) * HD + lane];
#pragma unroll
        for (int r = 0; r < 16; ++r) {
            const float4 x0 = *(const float4*)&Xs[rbase + r][k0 + 0];
            const float4 x1 = *(const float4*)&Xs[rbase + r][k0 + 4];
            float a = acc[r];
            a = fmaf(wreg[0], x0.x, a);
            a = fmaf(wreg[1], x0.y, a);
            a = fmaf(wreg[2], x0.z, a);
            a = fmaf(wreg[3], x0.w, a);
            a = fmaf(wreg[4], x1.x, a);
            a = fmaf(wreg[5], x1.y, a);
            a = fmaf(wreg[6], x1.z, a);
            a = fmaf(wreg[7], x1.w, a);
            acc[r] = a;
        }
    }

#pragma unroll
    for (int r = 0; r < 16; ++r) {
        const int row = row0 + rbase + r;
        if (row < n) Y[(size_t)row * HD + lane] = acc[r];
    }
}

// ---------------------------------------------------------------------------
// CSR build
// ---------------------------------------------------------------------------
__global__ __launch_bounds__(256) void count_deg(const int* __restrict__ dst,
                                                 int* __restrict__ deg, int E) {
    const int t = blockIdx.x * 256 + threadIdx.x;
    if (t < E) atomicAdd(&deg[dst[t]], 1);
}

__global__ __launch_bounds__(256) void assign_starts(const int* __restrict__ deg,
                                                     int* __restrict__ start,
                                                     int* __restrict__ fillpos,
                                                     int* __restrict__ cursor, int n) {
    const int t     = blockIdx.x * 256 + threadIdx.x;
    const int lane  = threadIdx.x & 63;
    const int base4 = t * 4;
    int d[4];
    int tot = 0;
#pragma unroll
    for (int i = 0; i < 4; ++i) {
        d[i] = (base4 + i < n) ? deg[base4 + i] : 0;
        tot += d[i];
    }
    int pfx = tot;
#pragma unroll
    for (int off = 1; off < 64; off <<= 1) {
        const int y = __shfl_up(pfx, off);
        if (lane >= off) pfx += y;
    }
    const int excl = pfx - tot;
    int base = 0;
    if (lane == 63) base = atomicAdd(cursor, pfx);
    base = __shfl(base, 63);
    int s = base + excl;
#pragma unroll
    for (int i = 0; i < 4; ++i) {
        if (base4 + i < n) {
            start[base4 + i]   = s;
            fillpos[base4 + i] = s;
        }
        s += d[i];
    }
}

__global__ __launch_bounds__(256) void fill_csr(const int* __restrict__ src,
                                                const int* __restrict__ dst,
                                                int* __restrict__ fillpos,
                                                int* __restrict__ eidx, int E) {
    const int t = blockIdx.x * 256 + threadIdx.x;
    if (t < E) {
        const int p = atomicAdd(&fillpos[dst[t]], 1);
        eidx[p] = src[t];
    }
}

// ---------------------------------------------------------------------------
// Quad-gather for node v: returns per-lane float4 = columns [(lane&15)*4 ..+3]
// of  Y[v] + sum_{u in N(v)} Y[u],  identical across the 4 lane-subsets.
// lane = (subset = lane>>4, colquad = lane&15). Each float4 load fetches 4
// DIFFERENT rows per instruction; 4 masked loads cover 16 edges back-to-back.
// ---------------------------------------------------------------------------
__device__ __forceinline__ float4 gather_quad(const float* __restrict__ Y,
                                              const int* __restrict__ eidx,
                                              int s, int e, int v, int lane) {
    const int sub = lane >> 4;       // 0..3  edge subset
    const int qo  = lane & 15;       // float4 index within a row
    const float4* Yq = (const float4*)Y;   // row = 16 float4s

    float4 a = make_float4(0.f, 0.f, 0.f, 0.f);
    if (sub == 0) a = Yq[(size_t)v * 16 + qo];   // self row via subset 0

    int base = s;
    while (base < e) {
        const int c   = min(64, e - base);
        const int myu = eidx[base + min(lane, c - 1)];  // clamped (no OOB)
#pragma unroll 1
        for (int i = 0; i < c; i += 16) {
            const int rem = c - i;   // 1..64
            const int u0 = __shfl(myu, i + 0  + sub);
            const int u1 = __shfl(myu, i + 4  + sub);
            const int u2 = __shfl(myu, i + 8  + sub);
            const int u3 = __shfl(myu, i + 12 + sub);
            float4 f0 = make_float4(0.f, 0.f, 0.f, 0.f);
            float4 f1 = make_float4(0.f, 0.f, 0.f, 0.f);
            float4 f2 = make_float4(0.f, 0.f, 0.f, 0.f);
            float4 f3 = make_float4(0.f, 0.f, 0.f, 0.f);
            if (sub < rem)      f0 = Yq[(size_t)u0 * 16 + qo];
            if (sub + 4 < rem)  f1 = Yq[(size_t)u1 * 16 + qo];
            if (sub + 8 < rem)  f2 = Yq[(size_t)u2 * 16 + qo];
            if (sub + 12 < rem) f3 = Yq[(size_t)u3 * 16 + qo];
            a.x += (f0.x + f1.x) + (f2.x + f3.x);
            a.y += (f0.y + f1.y) + (f2.y + f3.y);
            a.z += (f0.z + f1.z) + (f2.z + f3.z);
            a.w += (f0.w + f1.w) + (f2.w + f3.w);
        }
        base += c;
    }

    // reduce across the 4 subsets (lanes l, l^16, l^32, l^48)
    a.x += __shfl_xor(a.x, 16); a.y += __shfl_xor(a.y, 16);
    a.z += __shfl_xor(a.z, 16); a.w += __shfl_xor(a.w, 16);
    a.x += __shfl_xor(a.x, 32); a.y += __shfl_xor(a.y, 32);
    a.z += __shfl_xor(a.z, 32); a.w += __shfl_xor(a.w, 32);
    return a;
}

// ---------------------------------------------------------------------------
// Fused GIN layer (middle), barrier-free, 2-wave blocks (32 rows):
//   t = relu(gather + bpre) -> Xs ; h1 = relu(t@Wb+bb) -> Xs ; y2 = h1@Wn -> HBM
// ---------------------------------------------------------------------------
__global__ __launch_bounds__(128) void layer_mid(const float* __restrict__ Y,
                                                 const int* __restrict__ start,
                                                 const int* __restrict__ endp,
                                                 const int* __restrict__ eidx,
                                                 const float* __restrict__ bpre,
                                                 const float* __restrict__ Wb,
                                                 const float* __restrict__ bb,
                                                 const float* __restrict__ Wn,
                                                 float* __restrict__ Yout, int n) {
    __shared__ float Xs[32][HD];  // 8 KB

    const int lane  = threadIdx.x & 63;
    const int wid   = threadIdx.x >> 6;   // 0..1
    const int row0  = blockIdx.x * 32;
    const int rbase = wid * 16;
    const int qo    = lane & 15;

    const float4 bp4 = ((const float4*)bpre)[qo];
#pragma unroll 1
    for (int r = 0; r < 16; ++r) {
        const int v = row0 + rbase + r;
        float4 t4 = make_float4(0.f, 0.f, 0.f, 0.f);
        if (v < n) {
            float4 a = gather_quad(Y, eidx, start[v], endp[v], v, lane);
            t4.x = fmaxf(a.x + bp4.x, 0.f);
            t4.y = fmaxf(a.y + bp4.y, 0.f);
            t4.z = fmaxf(a.z + bp4.z, 0.f);
            t4.w = fmaxf(a.w + bp4.w, 0.f);
        }
        if (lane < 16) *(float4*)&Xs[rbase + r][qo * 4] = t4;
    }

    float acc[16];
#pragma unroll
    for (int r = 0; r < 16; ++r) acc[r] = 0.f;

#pragma unroll 1
    for (int k0 = 0; k0 < HD; k0 += 8) {
        float wreg[8];
#pragma unroll
        for (int j = 0; j < 8; ++j) wreg[j] = Wb[(k0 + j) * HD + lane];
#pragma unroll
        for (int r = 0; r < 16; ++r) {
            const float4 x0 = *(const float4*)&Xs[rbase + r][k0 + 0];
            const float4 x1 = *(const float4*)&Xs[rbase + r][k0 + 4];
            float a = acc[r];
            a = fmaf(wreg[0], x0.x, a);
            a = fmaf(wreg[1], x0.y, a);
            a = fmaf(wreg[2], x0.z, a);
            a = fmaf(wreg[3], x0.w, a);
            a = fmaf(wreg[4], x1.x, a);
            a = fmaf(wreg[5], x1.y, a);
            a = fmaf(wreg[6], x1.z, a);
            a = fmaf(wreg[7], x1.w, a);
            acc[r] = a;
        }
    }

    const float bbv = bb[lane];
#pragma unroll
    for (int r = 0; r < 16; ++r) Xs[rbase + r][lane] = fmaxf(acc[r] + bbv, 0.f);

    float acc2[16];
#pragma unroll
    for (int r = 0; r < 16; ++r) acc2[r] = 0.f;

#pragma unroll 1
    for (int k0 = 0; k0 < HD; k0 += 8) {
        float wreg[8];
#pragma unroll
        for (int j = 0; j < 8; ++j) wreg[j] = Wn[(k0 + j) * HD + lane];
#pragma unroll
        for (int r = 0; r < 16; ++r) {
            const float4 x0 = *(const float4*)&Xs[rbase + r][k0 + 0];
            const float4 x1 = *(const float4*)&Xs[rbase + r][k0 + 4];
            float a = acc2[r];
            a = fmaf(wreg[0], x0.x, a);
            a = fmaf(wreg[1], x0.y, a);
            a = fmaf(wreg[2], x0.z, a);
            a = fmaf(wreg[3], x0.w, a);
            a = fmaf(wreg[4], x1.x, a);
            a = fmaf(wreg[5], x1.y, a);
            a = fmaf(wreg[6], x1.z, a);
            a = fmaf(wreg[7], x1.w, a);
            acc2[r] = a;
        }
    }

#pragma unroll
    for (int r = 0; r < 16; ++r) {
        const int row = row0 + rbase + r;
        if (row < n) Yout[(size_t)row * HD + lane] = acc2[r];
    }
}

// ---------------------------------------------------------------------------
// Fused GIN layer (final) + pooling, barrier-free, 2-wave blocks.
// ---------------------------------------------------------------------------
__global__ __launch_bounds__(128) void layer_end(const float* __restrict__ Y,
                                                 const int* __restrict__ start,
                                                 const int* __restrict__ endp,
                                                 const int* __restrict__ eidx,
                                                 const float* __restrict__ bpre,
                                                 const float* __restrict__ Wb,
                                                 const float* __restrict__ bb,
                                                 const int* __restrict__ batch,
                                                 float* __restrict__ sums,
                                                 float* __restrict__ counts, int n) {
    __shared__ float Xs[32][HD];  // 8 KB

    const int lane  = threadIdx.x & 63;
    const int wid   = threadIdx.x >> 6;
    const int row0  = blockIdx.x * 32;
    const int rbase = wid * 16;
    const int qo    = lane & 15;

    const float4 bp4 = ((const float4*)bpre)[qo];
#pragma unroll 1
    for (int r = 0; r < 16; ++r) {
        const int v = row0 + rbase + r;
        float4 t4 = make_float4(0.f, 0.f, 0.f, 0.f);
        if (v < n) {
            float4 a = gather_quad(Y, eidx, start[v], endp[v], v, lane);
            t4.x = fmaxf(a.x + bp4.x, 0.f);
            t4.y = fmaxf(a.y + bp4.y, 0.f);
            t4.z = fmaxf(a.z + bp4.z, 0.f);
            t4.w = fmaxf(a.w + bp4.w, 0.f);
        }
        if (lane < 16) *(float4*)&Xs[rbase + r][qo * 4] = t4;
    }

    float acc[16];
#pragma unroll
    for (int r = 0; r < 16; ++r) acc[r] = 0.f;

#pragma unroll 1
    for (int k0 = 0; k0 < HD; k0 += 8) {
        float wreg[8];
#pragma unroll
        for (int j = 0; j < 8; ++j) wreg[j] = Wb[(k0 + j) * HD + lane];
#pragma unroll
        for (int r = 0; r < 16; ++r) {
            const float4 x0 = *(const float4*)&Xs[rbase + r][k0 + 0];
            const float4 x1 = *(const float4*)&Xs[rbase + r][k0 + 4];
            float a = acc[r];
            a = fmaf(wreg[0], x0.x, a);
            a = fmaf(wreg[1], x0.y, a);
            a = fmaf(wreg[2], x0.z, a);
            a = fmaf(wreg[3], x0.w, a);
            a = fmaf(wreg[4], x1.x, a);
            a = fmaf(wreg[5], x1.y, a);
            a = fmaf(wreg[6], x1.z, a);
            a = fmaf(wreg[7], x1.w, a);
            acc[r] = a;
        }
    }

    // h2 = relu(acc + bb); run-accumulate pool over 16 consecutive rows
    const float bbv = bb[lane];
    const int vbase = row0 + rbase;
    int   curg = -1;
    float racc = 0.f;
    float rcnt = 0.f;
#pragma unroll
    for (int r = 0; r < 16; ++r) {
        const int v = vbase + r;
        int g = -1;
        if (v < n) g = batch[v];               // wave-uniform
        if (g != curg) {
            if (curg >= 0) {
                unsafeAtomicAdd(&sums[(size_t)curg * HD + lane], racc);
                if (lane == 0) unsafeAtomicAdd(&counts[curg], rcnt);
            }
            curg = g;
            racc = 0.f;
            rcnt = 0.f;
        }
        if (g >= 0) {
            racc += fmaxf(acc[r] + bbv, 0.f);
            rcnt += 1.f;
        }
    }
    if (curg >= 0) {
        unsafeAtomicAdd(&sums[(size_t)curg * HD + lane], racc);
        if (lane == 0) unsafeAtomicAdd(&counts[curg], rcnt);
    }
}

// ---------------------------------------------------------------------------
// out[g][c] = (sums[g][:]/max(counts[g],1)) . Wf[:][c] + bf[c]
// ---------------------------------------------------------------------------
__global__ __launch_bounds__(256) void final_linear(const float* __restrict__ sums,
                                                    const float* __restrict__ counts,
                                                    const float* __restrict__ Wf,
                                                    const float* __restrict__ bfv,
                                                    float* __restrict__ out, int G, int C) {
    const int t = blockIdx.x * 256 + threadIdx.x;
    if (t >= G * C) return;
    const int g = t / C;
    const int c = t - g * C;
    const float inv = 1.0f / fmaxf(counts[g], 1.0f);
    float acc = 0.f;
    for (int h = 0; h < HD; ++h) acc += sums[(size_t)g * HD + h] * Wf[h * C + c];
    out[t] = acc * inv + bfv[c];
}

extern "C" void kernel_launch(void* const* d_in, const int* in_sizes, int n_in,
                              void* d_out, int out_size, void* d_ws, size_t ws_size,
                              hipStream_t stream) {
    const float* x    = (const float*)d_in[0];
    const int*   ei   = (const int*)d_in[1];
    const int*   batc = (const int*)d_in[2];
    const float* W1a  = (const float*)d_in[3];
    const float* b1a  = (const float*)d_in[4];
    const float* W1b  = (const float*)d_in[5];
    const float* b1b  = (const float*)d_in[6];
    const float* W2a  = (const float*)d_in[7];
    const float* b2a  = (const float*)d_in[8];
    const float* W2b  = (const float*)d_in[9];
    const float* b2b  = (const float*)d_in[10];
    const float* Wf   = (const float*)d_in[11];
    const float* bfv  = (const float*)d_in[12];

    const int n = in_sizes[2];       // 100000 nodes
    const int E = in_sizes[1] / 2;   // 1M edges
    const int C = in_sizes[12];      // 2 classes
    const int G = out_size / C;      // 1000 graphs

    const int* src = ei;
    const int* dst = ei + E;

    float* bufA   = (float*)d_ws;                  // n x 64  (y1)
    float* bufB   = bufA + (size_t)n * HD;         // n x 64  (y2)
    float* sums   = bufB + (size_t)n * HD;         // G x 64
    float* counts = sums + (size_t)G * HD;         // G
    int*   deg    = (int*)(counts + G);            // n
    int*   start  = deg + n;                       // n
    int*   fillp  = start + n;                     // n (== end after fill)
    int*   cursor = fillp + n;                     // 1
    int*   eidx   = cursor + 1;                    // E

    const int gemmGrid  = (n + 63) / 64;
    const int layerGrid = (n + 31) / 32;
    const int eGrid     = (E + 255) / 256;

    // ---- CSR build (once, reused by both layers)
    hipMemsetAsync(deg, 0, (size_t)n * sizeof(int), stream);
    hipMemsetAsync(cursor, 0, sizeof(int), stream);
    count_deg<<<eGrid, 256, 0, stream>>>(dst, deg, E);
    assign_starts<<<(n + 1023) / 1024, 256, 0, stream>>>(deg, start, fillp, cursor, n);
    fill_csr<<<eGrid, 256, 0, stream>>>(src, dst, fillp, eidx, E);

    // ---- y1 = x@W1a
    gemm_k<128><<<gemmGrid, 256, 0, stream>>>(x, W1a, bufA, n);

    // ---- Fused layer 1 + start of layer 2
    layer_mid<<<layerGrid, 128, 0, stream>>>(bufA, start, fillp, eidx,
                                             b1a, W1b, b1b, W2a, bufB, n);

    // ---- Fused layer 2 tail + pooling
    hipMemsetAsync(sums, 0, (size_t)G * (HD + 1) * sizeof(float), stream);
    layer_end<<<layerGrid, 128, 0, stream>>>(bufB, start, fillp, eidx,
                                             b2a, W2b, b2b, batc, sums, counts, n);

    // ---- Final linear
    final_linear<<<(G * C + 255) / 256, 256, 0, stream>>>(sums, counts, Wf, bfv,
                                                          (float*)d_out, G, C);
}